// Round 11
// baseline (388.411 us; speedup 1.0000x reference)
//
#include <hip/hip_runtime.h>
#include <hip/hip_bf16.h>

// SDPA with bias, materializing output + attention weights.
// B=4, H=8, T=2048, DK=64, fp32 in/out, bf16 MFMA 16x16x32 inside.
// Round 11: kill the P LDS round-trip (in-register 4-lane shuffle redistribution,
// 8x 64-bit __shfl) and the V LDS tile (V^T frags direct from global, L1/L2-
// resident, same access shape as the bias loads). LDS = K dbuf only (18.4KB)
// -> 3 blocks/CU at VGPR<=85 (launch_bounds 512,6). W stored f32 from regs
// (normal stores -- NOT nontemporal, r6 lesson). Soft barrier kept (r8).
#define TT   2048
#define DKK  64
#define NHH  8
#define NBB  4
#define QB   128
#define KBLK 64
#define NKT  (TT / KBLK)   // 32
#define LDE  72            // padded LDS row stride: bank-uniform for frag reads
#define TILE (KBLK * LDE)
#define SCALE 0.125f

// LDS-only barrier: waits own ds ops, syncs waves, does NOT drain vmcnt
#define SOFT_BARRIER() do {                                         \
    asm volatile("s_waitcnt lgkmcnt(0)" ::: "memory");              \
    __builtin_amdgcn_s_barrier();                                   \
    asm volatile("" ::: "memory");                                  \
} while (0)

typedef __attribute__((ext_vector_type(4))) float  f32x4;
typedef __attribute__((ext_vector_type(8))) __bf16 bf16x8;
typedef __attribute__((ext_vector_type(4))) __bf16 bf16x4;

union PK1 { unsigned long long u; bf16x4 v; };
union PK2 { unsigned long long u[2]; bf16x8 v; };

// ---- prepass 1: K fp32 -> bf16, same [bh][t][d] layout ----
__global__ __launch_bounds__(256)
void cast_k_kernel(const float* __restrict__ K, __bf16* __restrict__ Kb) {
    size_t i = ((size_t)blockIdx.x * 256 + threadIdx.x) * 8;
    f32x4 a = *(const f32x4*)(K + i);
    f32x4 b = *(const f32x4*)(K + i + 4);
    bf16x8 o = {(__bf16)a[0], (__bf16)a[1], (__bf16)a[2], (__bf16)a[3],
                (__bf16)b[0], (__bf16)b[1], (__bf16)b[2], (__bf16)b[3]};
    *(bf16x8*)(Kb + i) = o;
}

// ---- prepass 2: V fp32 [bh][t][d] -> bf16 transposed [bh][d][t] ----
__global__ __launch_bounds__(256)
void vt_kernel(const float* __restrict__ V, __bf16* __restrict__ Vt) {
    __shared__ __bf16 tile[DKK][72];
    const int bh = blockIdx.y;
    const int t0 = blockIdx.x * 64;
    const int tid = threadIdx.x;
    const float* Vb = V + ((size_t)bh * TT + t0) * DKK;
    #pragma unroll
    for (int i = 0; i < 4; ++i) {
        int idx = tid + i * 256;
        int row = idx >> 4, c4 = idx & 15;
        f32x4 v = *(const f32x4*)(Vb + row * DKK + c4 * 4);
        tile[c4 * 4 + 0][row] = (__bf16)v[0];
        tile[c4 * 4 + 1][row] = (__bf16)v[1];
        tile[c4 * 4 + 2][row] = (__bf16)v[2];
        tile[c4 * 4 + 3][row] = (__bf16)v[3];
    }
    __syncthreads();
    __bf16* out = Vt + (size_t)bh * DKK * TT + t0;
    #pragma unroll
    for (int i = 0; i < 2; ++i) {
        int idx = tid + i * 256;
        int d = idx >> 3, ch = idx & 7;
        bf16x8 o = *(const bf16x8*)&tile[d][ch * 8];
        *(bf16x8*)(out + (size_t)d * TT + ch * 8) = o;
    }
}

// ---- main: 8 q-waves, 128 q-rows/block ----
__global__ __launch_bounds__(512, 6)
void sdpa_main(const float* __restrict__ Qp, const float* __restrict__ Bp,
               const __bf16* __restrict__ Kb, const __bf16* __restrict__ Vt,
               float* __restrict__ Op, float* __restrict__ Wp)
{
    __shared__ __bf16 Kl[2][TILE];     // K tile double buffer [key][d] -- only LDS

    const int tid  = threadIdx.x;
    const int lane = tid & 63;
    const int w    = tid >> 6;     // 0..7 : q rows w*16..+15
    const int g    = lane >> 4;    // 0..3
    const int ql   = lane & 15;

    // XCD-aware decode: h = id&7 pins each head's bias slice to one XCD.
    const int id  = blockIdx.x;    // 0..511
    const int h   = id & 7;
    const int r   = id >> 3;       // 0..63
    const int qt  = r & 15;        // 0..15
    const int b   = r >> 4;        // 0..3
    const int bh  = b * NHH + h;

    const int q_local = w * 16 + ql;
    const int q_glob  = qt * QB + q_local;

    const __bf16* Kbh = Kb + (size_t)bh * TT * DKK;   // [key][d]
    const __bf16* Vbh = Vt + (size_t)bh * DKK * TT;   // [d][key]
    const float* biasRow = Bp + ((size_t)h * TT + q_glob) * TT;
    float* Wrow = Wp + ((size_t)bh * TT + q_glob) * TT;

    // staging map: 512 threads x 16B = one 64x64 bf16 tile
    const int srow = tid >> 3;     // 0..63
    const int sch  = tid & 7;      // 0..7

    // Q fragments (B-operand): lane holds Q[q_glob][d = 8g+j (+32)]
    const float* qrow = Qp + ((size_t)bh * TT + q_glob) * DKK;
    f32x4 qa = *(const f32x4*)(qrow + g * 8);
    f32x4 qc = *(const f32x4*)(qrow + g * 8 + 4);
    f32x4 qe = *(const f32x4*)(qrow + 32 + g * 8);
    f32x4 qf = *(const f32x4*)(qrow + 32 + g * 8 + 4);
    const bf16x8 qfrag0 = {(__bf16)qa[0], (__bf16)qa[1], (__bf16)qa[2], (__bf16)qa[3],
                           (__bf16)qc[0], (__bf16)qc[1], (__bf16)qc[2], (__bf16)qc[3]};
    const bf16x8 qfrag1 = {(__bf16)qe[0], (__bf16)qe[1], (__bf16)qe[2], (__bf16)qe[3],
                           (__bf16)qf[0], (__bf16)qf[1], (__bf16)qf[2], (__bf16)qf[3]};

    // ================= phase 1: l = sum exp(s) over all keys =============
    *(bf16x8*)&Kl[0][srow * LDE + sch * 8] =
        *(const bf16x8*)(Kbh + (size_t)srow * DKK + sch * 8);
    __syncthreads();

    f32x4 lacc = {0.f, 0.f, 0.f, 0.f};
    for (int kt = 0; kt < NKT; ++kt) {
        const int cur = kt & 1;
        const bool more = (kt + 1 < NKT);
        bf16x8 kreg;
        if (more)  // prefetch next K tile into regs (issue early)
            kreg = *(const bf16x8*)(Kbh + ((size_t)(kt + 1) * KBLK + srow) * DKK + sch * 8);
        const float* bp = biasRow + kt * KBLK;
        f32x4 bv[4];
        #pragma unroll
        for (int s = 0; s < 4; ++s) bv[s] = *(const f32x4*)(bp + s * 16 + g * 4);

        f32x4 acc[4] = {};
        #pragma unroll
        for (int s = 0; s < 4; ++s) {
            bf16x8 a0 = *(const bf16x8*)&Kl[cur][(s * 16 + ql) * LDE + g * 8];
            acc[s] = __builtin_amdgcn_mfma_f32_16x16x32_bf16(a0, qfrag0, acc[s], 0, 0, 0);
            bf16x8 a1 = *(const bf16x8*)&Kl[cur][(s * 16 + ql) * LDE + 32 + g * 8];
            acc[s] = __builtin_amdgcn_mfma_f32_16x16x32_bf16(a1, qfrag1, acc[s], 0, 0, 0);
        }
        #pragma unroll
        for (int s = 0; s < 4; ++s) {
            f32x4 x = acc[s] * SCALE + bv[s];
            lacc[0] += __expf(x[0]);
            lacc[1] += __expf(x[1]);
            lacc[2] += __expf(x[2]);
            lacc[3] += __expf(x[3]);
        }
        if (more)  // write-late: latency hidden under this iter's compute
            *(bf16x8*)&Kl[cur ^ 1][srow * LDE + sch * 8] = kreg;
        SOFT_BARRIER();
    }
    float l_run = lacc[0] + lacc[1] + lacc[2] + lacc[3];
    l_run += __shfl_xor(l_run, 16);
    l_run += __shfl_xor(l_run, 32);
    const float inv_l = 1.0f / l_run;

    // ================= phase 2: recompute, write W, accumulate PV ========
    *(bf16x8*)&Kl[0][srow * LDE + sch * 8] =
        *(const bf16x8*)(Kbh + (size_t)srow * DKK + sch * 8);
    __syncthreads();

    const int laneA = ql + ((g & 1) << 5);   // shuffle source lanes (same q row)
    const bool selHi = (g >> 1) != 0;

    f32x4 oacc[4] = {};            // O^T[d = m*16+4g+r][q_local]
    for (int kt = 0; kt < NKT; ++kt) {
        const int cur = kt & 1;
        const bool more = (kt + 1 < NKT);
        bf16x8 kreg;
        if (more)
            kreg = *(const bf16x8*)(Kbh + ((size_t)(kt + 1) * KBLK + srow) * DKK + sch * 8);
        const float* bp = biasRow + kt * KBLK;
        f32x4 bv[4];
        #pragma unroll
        for (int s = 0; s < 4; ++s) bv[s] = *(const f32x4*)(bp + s * 16 + g * 4);

        f32x4 acc[4] = {};
        #pragma unroll
        for (int s = 0; s < 4; ++s) {
            bf16x8 a0 = *(const bf16x8*)&Kl[cur][(s * 16 + ql) * LDE + g * 8];
            acc[s] = __builtin_amdgcn_mfma_f32_16x16x32_bf16(a0, qfrag0, acc[s], 0, 0, 0);
            bf16x8 a1 = *(const bf16x8*)&Kl[cur][(s * 16 + ql) * LDE + 32 + g * 8];
            acc[s] = __builtin_amdgcn_mfma_f32_16x16x32_bf16(a1, qfrag1, acc[s], 0, 0, 0);
        }
        // softmax weights: lane (ql,g) holds W[q=16w+ql][k=16s+4g+r]
        unsigned long long pbu0, pbu1, pbu2, pbu3;
        #pragma unroll
        for (int s = 0; s < 4; ++s) {
            f32x4 x = acc[s] * SCALE + bv[s];
            f32x4 wq;
            wq[0] = __expf(x[0]) * inv_l;
            wq[1] = __expf(x[1]) * inv_l;
            wq[2] = __expf(x[2]) * inv_l;
            wq[3] = __expf(x[3]) * inv_l;
            // W store: f32 direct from regs (64B per ql-row per instr across g)
            *(f32x4*)(Wrow + kt * KBLK + s * 16 + g * 4) = wq;
            PK1 pk; pk.v = bf16x4{(__bf16)wq[0], (__bf16)wq[1], (__bf16)wq[2], (__bf16)wq[3]};
            if (s == 0) pbu0 = pk.u; else if (s == 1) pbu1 = pk.u;
            else if (s == 2) pbu2 = pk.u; else pbu3 = pk.u;
        }
        // in-register P redistribution: PV needs lane (ql,g) <- P[q][k=8g+j]
        unsigned long long yA0 = __shfl(pbu0, laneA);
        unsigned long long yA1 = __shfl(pbu1, laneA);
        unsigned long long yA2 = __shfl(pbu2, laneA);
        unsigned long long yA3 = __shfl(pbu3, laneA);
        unsigned long long yB0 = __shfl(pbu0, laneA + 16);
        unsigned long long yB1 = __shfl(pbu1, laneA + 16);
        unsigned long long yB2 = __shfl(pbu2, laneA + 16);
        unsigned long long yB3 = __shfl(pbu3, laneA + 16);
        PK2 p0, p1;
        p0.u[0] = selHi ? yA1 : yA0;   // k = 8g .. 8g+3
        p0.u[1] = selHi ? yB1 : yB0;   // k = 8g+4 .. 8g+7
        p1.u[0] = selHi ? yA3 : yA2;   // k = 32+8g .. +3
        p1.u[1] = selHi ? yB3 : yB2;   // k = 32+8g+4 .. +7
        const bf16x8 bp0 = p0.v;
        const bf16x8 bp1 = p1.v;
        // PV: V^T fragments direct from global (L1/L2-resident window)
        #pragma unroll
        for (int m = 0; m < 4; ++m) {
            bf16x8 av0 = *(const bf16x8*)(Vbh + (size_t)(m * 16 + ql) * TT + kt * KBLK + g * 8);
            oacc[m] = __builtin_amdgcn_mfma_f32_16x16x32_bf16(av0, bp0, oacc[m], 0, 0, 0);
            bf16x8 av1 = *(const bf16x8*)(Vbh + (size_t)(m * 16 + ql) * TT + kt * KBLK + 32 + g * 8);
            oacc[m] = __builtin_amdgcn_mfma_f32_16x16x32_bf16(av1, bp1, oacc[m], 0, 0, 0);
        }
        if (more)  // write-late staging, then the soft barrier
            *(bf16x8*)&Kl[cur ^ 1][srow * LDE + sch * 8] = kreg;
        SOFT_BARRIER();
    }

    // ---- store O: oacc[m][r] = O[q_glob][m*16+4g+r] ----
    float* Orow = Op + ((size_t)bh * TT + q_glob) * DKK;
    #pragma unroll
    for (int m = 0; m < 4; ++m)
        *(f32x4*)(Orow + m * 16 + g * 4) = oacc[m];
}

extern "C" void kernel_launch(void* const* d_in, const int* in_sizes, int n_in,
                              void* d_out, int out_size, void* d_ws, size_t ws_size,
                              hipStream_t stream) {
    const float* Q  = (const float*)d_in[0];
    const float* K  = (const float*)d_in[1];
    const float* V  = (const float*)d_in[2];
    const float* Bs = (const float*)d_in[3];
    float* Out = (float*)d_out;
    float* W   = Out + (size_t)NBB * NHH * TT * DKK;

    const size_t nElem = (size_t)NBB * NHH * TT * DKK;
    __bf16* Kb = (__bf16*)d_ws;
    __bf16* Vt = Kb + nElem;

    cast_k_kernel<<<dim3(nElem / 8 / 256), dim3(256), 0, stream>>>(K, Kb);
    vt_kernel<<<dim3(TT / 64, NBB * NHH), dim3(256), 0, stream>>>(V, Vt);
    sdpa_main<<<dim3((TT / QB) * NBB * NHH), dim3(512), 0, stream>>>(Q, Bs, Kb, Vt, Out, W);
}

// Round 12
// 320.359 us; speedup vs baseline: 1.2124x; 1.2124x over previous
//
#include <hip/hip_runtime.h>
#include <hip/hip_bf16.h>

// SDPA with bias, materializing output + attention weights.
// B=4, H=8, T=2048, DK=64, fp32 in/out, bf16 MFMA 16x16x32 inside.
// Round 12: 2-way k-split inside the r5/r8 tile. QB=64; 8 waves = 4 q-waves
// x 2 k-groups; kg0 handles keys 0..31 of the staged 64-key tile, kg1 keys
// 32..63. Staging identical to r5. Per-wave LDS frag reads halve (the DS unit
// was the largest convoy term); grid 1024 blocks; LDS ~48KB -> 3 blocks/CU
// (75% occupancy). l-combine + O-combine once via LDS. Soft barrier kept.
#define TT   2048
#define DKK  64
#define NHH  8
#define NBB  4
#define QB   64
#define KBLK 64
#define NKT  (TT / KBLK)   // 32
#define LDE  72            // padded LDS row stride (bf16): bank-uniform frags
#define TILE (KBLK * LDE)
#define PLDE 40            // P row stride (32 keys + 8 pad)
#define SCALE 0.125f

// LDS-only barrier: waits own ds ops, syncs waves, does NOT drain vmcnt
#define SOFT_BARRIER() do {                                         \
    asm volatile("s_waitcnt lgkmcnt(0)" ::: "memory");              \
    __builtin_amdgcn_s_barrier();                                   \
    asm volatile("" ::: "memory");                                  \
} while (0)

typedef __attribute__((ext_vector_type(4))) float  f32x4;
typedef __attribute__((ext_vector_type(8))) __bf16 bf16x8;
typedef __attribute__((ext_vector_type(4))) __bf16 bf16x4;

// ---- prepass 1: K fp32 -> bf16, same [bh][t][d] layout ----
__global__ __launch_bounds__(256)
void cast_k_kernel(const float* __restrict__ K, __bf16* __restrict__ Kb) {
    size_t i = ((size_t)blockIdx.x * 256 + threadIdx.x) * 8;
    f32x4 a = *(const f32x4*)(K + i);
    f32x4 b = *(const f32x4*)(K + i + 4);
    bf16x8 o = {(__bf16)a[0], (__bf16)a[1], (__bf16)a[2], (__bf16)a[3],
                (__bf16)b[0], (__bf16)b[1], (__bf16)b[2], (__bf16)b[3]};
    *(bf16x8*)(Kb + i) = o;
}

// ---- prepass 2: V fp32 [bh][t][d] -> bf16 transposed [bh][d][t] ----
__global__ __launch_bounds__(256)
void vt_kernel(const float* __restrict__ V, __bf16* __restrict__ Vt) {
    __shared__ __bf16 tile[DKK][72];
    const int bh = blockIdx.y;
    const int t0 = blockIdx.x * 64;
    const int tid = threadIdx.x;
    const float* Vb = V + ((size_t)bh * TT + t0) * DKK;
    #pragma unroll
    for (int i = 0; i < 4; ++i) {
        int idx = tid + i * 256;
        int row = idx >> 4, c4 = idx & 15;
        f32x4 v = *(const f32x4*)(Vb + row * DKK + c4 * 4);
        tile[c4 * 4 + 0][row] = (__bf16)v[0];
        tile[c4 * 4 + 1][row] = (__bf16)v[1];
        tile[c4 * 4 + 2][row] = (__bf16)v[2];
        tile[c4 * 4 + 3][row] = (__bf16)v[3];
    }
    __syncthreads();
    __bf16* out = Vt + (size_t)bh * DKK * TT + t0;
    #pragma unroll
    for (int i = 0; i < 2; ++i) {
        int idx = tid + i * 256;
        int d = idx >> 3, ch = idx & 7;
        bf16x8 o = *(const bf16x8*)&tile[d][ch * 8];
        *(bf16x8*)(out + (size_t)d * TT + ch * 8) = o;
    }
}

// ---- main: 8 waves = 4 q-waves x 2 k-groups, 64 q-rows/block ----
__global__ __launch_bounds__(512, 6)
void sdpa_main(const float* __restrict__ Qp, const float* __restrict__ Bp,
               const __bf16* __restrict__ Kb, const __bf16* __restrict__ Vt,
               float* __restrict__ Op, float* __restrict__ Wp)
{
    __shared__ __bf16 Kl[2][TILE];       // K tile double buffer [key][d]
    __shared__ __bf16 Vl[2][TILE];       // V^T tile double buffer [d][key]
    __shared__ __bf16 Pl[8][16 * PLDE];  // wave-private P [16 q][32 k]
    __shared__ float  Sst[8][16];        // per-wave per-q partial l

    const int tid  = threadIdx.x;
    const int lane = tid & 63;
    const int w    = tid >> 6;     // 0..7
    const int kg   = w >> 2;       // k-group 0/1: keys kg*32..+31 of the tile
    const int qw   = w & 3;        // q-wave: rows qw*16..+15
    const int g    = lane >> 4;    // 0..3
    const int ql   = lane & 15;

    // XCD-aware decode: h = id&7 pins each head's bias slice to one XCD.
    const int id  = blockIdx.x;    // 0..1023
    const int h   = id & 7;
    const int r   = id >> 3;       // 0..127
    const int qt  = r & 31;        // 0..31
    const int b   = r >> 5;        // 0..3
    const int bh  = b * NHH + h;

    const int q_local = qw * 16 + ql;
    const int q_glob  = qt * QB + q_local;

    const __bf16* Kbh = Kb + (size_t)bh * TT * DKK;   // [key][d]
    const __bf16* Vbh = Vt + (size_t)bh * DKK * TT;   // [d][key]
    const float* biasRow = Bp + ((size_t)h * TT + q_glob) * TT;
    float* Wrow = Wp + ((size_t)bh * TT + q_glob) * TT;

    // staging map: 512 threads x 16B = one 64x64 bf16 tile (identical to r5)
    const int srow = tid >> 3;     // 0..63
    const int sch  = tid & 7;      // 0..7

    // Q fragments (B-operand): lane holds Q[q_glob][d = 8g+j (+32)]
    const float* qrow = Qp + ((size_t)bh * TT + q_glob) * DKK;
    f32x4 qa = *(const f32x4*)(qrow + g * 8);
    f32x4 qc = *(const f32x4*)(qrow + g * 8 + 4);
    f32x4 qe = *(const f32x4*)(qrow + 32 + g * 8);
    f32x4 qf = *(const f32x4*)(qrow + 32 + g * 8 + 4);
    const bf16x8 qfrag0 = {(__bf16)qa[0], (__bf16)qa[1], (__bf16)qa[2], (__bf16)qa[3],
                           (__bf16)qc[0], (__bf16)qc[1], (__bf16)qc[2], (__bf16)qc[3]};
    const bf16x8 qfrag1 = {(__bf16)qe[0], (__bf16)qe[1], (__bf16)qe[2], (__bf16)qe[3],
                           (__bf16)qf[0], (__bf16)qf[1], (__bf16)qf[2], (__bf16)qf[3]};

    // ================= phase 1: partial l over this kg's key halves ======
    *(bf16x8*)&Kl[0][srow * LDE + sch * 8] =
        *(const bf16x8*)(Kbh + (size_t)srow * DKK + sch * 8);
    __syncthreads();

    f32x4 lacc = {0.f, 0.f, 0.f, 0.f};
    for (int kt = 0; kt < NKT; ++kt) {
        const int cur = kt & 1;
        const bool more = (kt + 1 < NKT);
        bf16x8 kreg;
        if (more)
            kreg = *(const bf16x8*)(Kbh + ((size_t)(kt + 1) * KBLK + srow) * DKK + sch * 8);
        const float* bp = biasRow + kt * KBLK + kg * 32;
        f32x4 bv[2];
        #pragma unroll
        for (int s = 0; s < 2; ++s) bv[s] = *(const f32x4*)(bp + s * 16 + g * 4);

        f32x4 acc[2] = {};
        #pragma unroll
        for (int s = 0; s < 2; ++s) {
            const int krow = (kg * 2 + s) * 16 + ql;
            bf16x8 a0 = *(const bf16x8*)&Kl[cur][krow * LDE + g * 8];
            acc[s] = __builtin_amdgcn_mfma_f32_16x16x32_bf16(a0, qfrag0, acc[s], 0, 0, 0);
            bf16x8 a1 = *(const bf16x8*)&Kl[cur][krow * LDE + 32 + g * 8];
            acc[s] = __builtin_amdgcn_mfma_f32_16x16x32_bf16(a1, qfrag1, acc[s], 0, 0, 0);
        }
        #pragma unroll
        for (int s = 0; s < 2; ++s) {
            f32x4 x = acc[s] * SCALE + bv[s];
            lacc[0] += __expf(x[0]);
            lacc[1] += __expf(x[1]);
            lacc[2] += __expf(x[2]);
            lacc[3] += __expf(x[3]);
        }
        if (more)
            *(bf16x8*)&Kl[cur ^ 1][srow * LDE + sch * 8] = kreg;
        SOFT_BARRIER();
    }
    float l_run = lacc[0] + lacc[1] + lacc[2] + lacc[3];
    l_run += __shfl_xor(l_run, 16);
    l_run += __shfl_xor(l_run, 32);
    // combine across the two k-groups (waves w and w^4 share q rows)
    if (g == 0) Sst[w][ql] = l_run;
    __syncthreads();
    l_run += Sst[w ^ 4][ql];
    const float inv_l = 1.0f / l_run;

    // ================= phase 2: recompute, write W, partial PV ===========
    *(bf16x8*)&Kl[0][srow * LDE + sch * 8] =
        *(const bf16x8*)(Kbh + (size_t)srow * DKK + sch * 8);
    *(bf16x8*)&Vl[0][srow * LDE + sch * 8] =
        *(const bf16x8*)(Vbh + (size_t)srow * TT + sch * 8);
    __syncthreads();

    f32x4 oacc[4] = {};            // partial O^T[d = m*16+4g+r][q_local]
    const int wrow8 = lane >> 3;   // W-flush row sub-index 0..7
    const int wch   = lane & 7;    // W-flush 16B chunk 0..7 (128B span)

    for (int kt = 0; kt < NKT; ++kt) {
        const int cur = kt & 1;
        const bool more = (kt + 1 < NKT);
        bf16x8 kreg, vreg;
        if (more) {
            kreg = *(const bf16x8*)(Kbh + ((size_t)(kt + 1) * KBLK + srow) * DKK + sch * 8);
            vreg = *(const bf16x8*)(Vbh + (size_t)srow * TT + (kt + 1) * KBLK + sch * 8);
        }
        const float* bp = biasRow + kt * KBLK + kg * 32;
        f32x4 bv[2];
        #pragma unroll
        for (int s = 0; s < 2; ++s) bv[s] = *(const f32x4*)(bp + s * 16 + g * 4);

        f32x4 acc[2] = {};
        #pragma unroll
        for (int s = 0; s < 2; ++s) {
            const int krow = (kg * 2 + s) * 16 + ql;
            bf16x8 a0 = *(const bf16x8*)&Kl[cur][krow * LDE + g * 8];
            acc[s] = __builtin_amdgcn_mfma_f32_16x16x32_bf16(a0, qfrag0, acc[s], 0, 0, 0);
            bf16x8 a1 = *(const bf16x8*)&Kl[cur][krow * LDE + 32 + g * 8];
            acc[s] = __builtin_amdgcn_mfma_f32_16x16x32_bf16(a1, qfrag1, acc[s], 0, 0, 0);
        }
        // P = softmax weights (bf16) into wave-private tile [16q][32k]
        #pragma unroll
        for (int s = 0; s < 2; ++s) {
            f32x4 x = acc[s] * SCALE + bv[s];
            bf16x4 pb = {(__bf16)(__expf(x[0]) * inv_l), (__bf16)(__expf(x[1]) * inv_l),
                         (__bf16)(__expf(x[2]) * inv_l), (__bf16)(__expf(x[3]) * inv_l)};
            *(bf16x4*)&Pl[w][ql * PLDE + s * 16 + g * 4] = pb;
        }
        // PV: one B frag (K-dim 32), 4 MFMA over d-blocks
        const bf16x8 bp0 = *(const bf16x8*)&Pl[w][ql * PLDE + g * 8];
        #pragma unroll
        for (int m = 0; m < 4; ++m) {
            bf16x8 av = *(const bf16x8*)&Vl[cur][(m * 16 + ql) * LDE + kg * 32 + g * 8];
            oacc[m] = __builtin_amdgcn_mfma_f32_16x16x32_bf16(av, bp0, oacc[m], 0, 0, 0);
        }
        // W store: wave's 16 rows x 128B (own kg's 32 cols), 2 instrs x 8 rows
        #pragma unroll
        for (int i = 0; i < 2; ++i) {
            const int row = i * 8 + wrow8;             // 0..15 within wave
            bf16x4 pw = *(const bf16x4*)&Pl[w][row * PLDE + wch * 4];
            f32x4 ow = {(float)pw[0], (float)pw[1], (float)pw[2], (float)pw[3]};
            *(f32x4*)(Wp + ((size_t)bh * TT + qt * QB + qw * 16 + row) * TT
                          + kt * KBLK + kg * 32 + wch * 4) = ow;
        }
        if (more) {
            *(bf16x8*)&Kl[cur ^ 1][srow * LDE + sch * 8] = kreg;
            *(bf16x8*)&Vl[cur ^ 1][srow * LDE + sch * 8] = vreg;
        }
        SOFT_BARRIER();
    }

    // ---- combine partial O across k-groups, store ----
    float* Os = (float*)&Kl[0][0];       // [64 q][68 d] f32 scratch (17.4KB)
    __syncthreads();                     // all PV reads of Kl done
    if (kg == 1) {
        #pragma unroll
        for (int m = 0; m < 4; ++m)
            *(f32x4*)&Os[q_local * 68 + m * 16 + g * 4] = oacc[m];
    }
    __syncthreads();
    if (kg == 0) {
        float* Orow = Op + ((size_t)bh * TT + q_glob) * DKK;
        #pragma unroll
        for (int m = 0; m < 4; ++m) {
            f32x4 o = oacc[m] + *(const f32x4*)&Os[q_local * 68 + m * 16 + g * 4];
            *(f32x4*)(Orow + m * 16 + g * 4) = o;
        }
    }
}

extern "C" void kernel_launch(void* const* d_in, const int* in_sizes, int n_in,
                              void* d_out, int out_size, void* d_ws, size_t ws_size,
                              hipStream_t stream) {
    const float* Q  = (const float*)d_in[0];
    const float* K  = (const float*)d_in[1];
    const float* V  = (const float*)d_in[2];
    const float* Bs = (const float*)d_in[3];
    float* Out = (float*)d_out;
    float* W   = Out + (size_t)NBB * NHH * TT * DKK;

    const size_t nElem = (size_t)NBB * NHH * TT * DKK;
    __bf16* Kb = (__bf16*)d_ws;
    __bf16* Vt = Kb + nElem;

    cast_k_kernel<<<dim3(nElem / 8 / 256), dim3(256), 0, stream>>>(K, Kb);
    vt_kernel<<<dim3(TT / 64, NBB * NHH), dim3(256), 0, stream>>>(V, Vt);
    sdpa_main<<<dim3((TT / QB) * NBB * NHH), dim3(512), 0, stream>>>(Q, Bs, Kb, Vt, Out, W);
}

// Round 13
// 204.946 us; speedup vs baseline: 1.8952x; 1.5631x over previous
//
#include <hip/hip_runtime.h>
#include <hip/hip_bf16.h>

// SDPA with bias, materializing output + attention weights.
// B=4, H=8, T=2048, DK=64, fp32 in/out, bf16 MFMA 16x16x32 inside.
// Round 13: r8 EXACTLY (best family: 263us) + ONE change: W and O stores are
// nontemporal. W (512MB, write-once-never-read) was streaming through L2/L3
// evicting the bias (logically re-read 4x = 512MB); r12's FETCH blow-up (227
// ->467MB) exposed this. Same store addressing (4-row x 256B cooperative from
// Pl); only the cache hint changes. r6's hidden win, unbundled from V-direct.
#define TT   2048
#define DKK  64
#define NHH  8
#define NBB  4
#define QB   128
#define KBLK 64
#define NKT  (TT / KBLK)   // 32
#define LDE  72            // padded LDS row stride: bank-uniform for frag reads
#define TILE (KBLK * LDE)
#define SCALE 0.125f

// LDS-only barrier: waits own ds ops, syncs waves, does NOT drain vmcnt
#define SOFT_BARRIER() do {                                         \
    asm volatile("s_waitcnt lgkmcnt(0)" ::: "memory");              \
    __builtin_amdgcn_s_barrier();                                   \
    asm volatile("" ::: "memory");                                  \
} while (0)

typedef __attribute__((ext_vector_type(4))) float  f32x4;
typedef __attribute__((ext_vector_type(8))) __bf16 bf16x8;
typedef __attribute__((ext_vector_type(4))) __bf16 bf16x4;

// ---- prepass 1: K fp32 -> bf16, same [bh][t][d] layout ----
__global__ __launch_bounds__(256)
void cast_k_kernel(const float* __restrict__ K, __bf16* __restrict__ Kb) {
    size_t i = ((size_t)blockIdx.x * 256 + threadIdx.x) * 8;
    f32x4 a = *(const f32x4*)(K + i);
    f32x4 b = *(const f32x4*)(K + i + 4);
    bf16x8 o = {(__bf16)a[0], (__bf16)a[1], (__bf16)a[2], (__bf16)a[3],
                (__bf16)b[0], (__bf16)b[1], (__bf16)b[2], (__bf16)b[3]};
    *(bf16x8*)(Kb + i) = o;
}

// ---- prepass 2: V fp32 [bh][t][d] -> bf16 transposed [bh][d][t] ----
__global__ __launch_bounds__(256)
void vt_kernel(const float* __restrict__ V, __bf16* __restrict__ Vt) {
    __shared__ __bf16 tile[DKK][72];
    const int bh = blockIdx.y;
    const int t0 = blockIdx.x * 64;
    const int tid = threadIdx.x;
    const float* Vb = V + ((size_t)bh * TT + t0) * DKK;
    #pragma unroll
    for (int i = 0; i < 4; ++i) {
        int idx = tid + i * 256;
        int row = idx >> 4, c4 = idx & 15;
        f32x4 v = *(const f32x4*)(Vb + row * DKK + c4 * 4);
        tile[c4 * 4 + 0][row] = (__bf16)v[0];
        tile[c4 * 4 + 1][row] = (__bf16)v[1];
        tile[c4 * 4 + 2][row] = (__bf16)v[2];
        tile[c4 * 4 + 3][row] = (__bf16)v[3];
    }
    __syncthreads();
    __bf16* out = Vt + (size_t)bh * DKK * TT + t0;
    #pragma unroll
    for (int i = 0; i < 2; ++i) {
        int idx = tid + i * 256;
        int d = idx >> 3, ch = idx & 7;
        bf16x8 o = *(const bf16x8*)&tile[d][ch * 8];
        *(bf16x8*)(out + (size_t)d * TT + ch * 8) = o;
    }
}

// ---- main: 8 q-waves, 128 q-rows/block, 1 soft barrier per k-iteration ----
__global__ __launch_bounds__(512, 4)
void sdpa_main(const float* __restrict__ Qp, const float* __restrict__ Bp,
               const __bf16* __restrict__ Kb, const __bf16* __restrict__ Vt,
               float* __restrict__ Op, float* __restrict__ Wp)
{
    __shared__ __bf16 Kl[2][TILE];     // K tile double buffer [key][d]
    __shared__ __bf16 Vl[2][TILE];     // V^T tile double buffer [d][key]
    __shared__ __bf16 Pl[8][16 * LDE]; // wave-private P [q][key]

    const int tid  = threadIdx.x;
    const int lane = tid & 63;
    const int w    = tid >> 6;     // 0..7 : q rows w*16..+15
    const int g    = lane >> 4;    // 0..3
    const int ql   = lane & 15;

    // XCD-aware decode: h = id&7 pins each head's bias slice to one XCD.
    const int id  = blockIdx.x;    // 0..511
    const int h   = id & 7;
    const int r   = id >> 3;       // 0..63
    const int qt  = r & 15;        // 0..15
    const int b   = r >> 4;        // 0..3
    const int bh  = b * NHH + h;

    const int q_local = w * 16 + ql;
    const int q_glob  = qt * QB + q_local;

    const __bf16* Kbh = Kb + (size_t)bh * TT * DKK;   // [key][d]
    const __bf16* Vbh = Vt + (size_t)bh * DKK * TT;   // [d][key]
    const float* biasRow = Bp + ((size_t)h * TT + q_glob) * TT;

    // staging map: 512 threads x 16B = one 64x64 bf16 tile
    const int srow = tid >> 3;     // 0..63
    const int sch  = tid & 7;      // 0..7

    // Q fragments (B-operand): lane holds Q[q_glob][d = 8g+j (+32)]
    const float* qrow = Qp + ((size_t)bh * TT + q_glob) * DKK;
    f32x4 qa = *(const f32x4*)(qrow + g * 8);
    f32x4 qc = *(const f32x4*)(qrow + g * 8 + 4);
    f32x4 qe = *(const f32x4*)(qrow + 32 + g * 8);
    f32x4 qf = *(const f32x4*)(qrow + 32 + g * 8 + 4);
    const bf16x8 qfrag0 = {(__bf16)qa[0], (__bf16)qa[1], (__bf16)qa[2], (__bf16)qa[3],
                           (__bf16)qc[0], (__bf16)qc[1], (__bf16)qc[2], (__bf16)qc[3]};
    const bf16x8 qfrag1 = {(__bf16)qe[0], (__bf16)qe[1], (__bf16)qe[2], (__bf16)qe[3],
                           (__bf16)qf[0], (__bf16)qf[1], (__bf16)qf[2], (__bf16)qf[3]};

    // ================= phase 1: l = sum exp(s) over all keys =============
    *(bf16x8*)&Kl[0][srow * LDE + sch * 8] =
        *(const bf16x8*)(Kbh + (size_t)srow * DKK + sch * 8);
    __syncthreads();

    f32x4 lacc = {0.f, 0.f, 0.f, 0.f};
    for (int kt = 0; kt < NKT; ++kt) {
        const int cur = kt & 1;
        const bool more = (kt + 1 < NKT);
        bf16x8 kreg;
        if (more)  // prefetch next K tile into regs (issue early)
            kreg = *(const bf16x8*)(Kbh + ((size_t)(kt + 1) * KBLK + srow) * DKK + sch * 8);
        const float* bp = biasRow + kt * KBLK;
        f32x4 bv[4];
        #pragma unroll
        for (int s = 0; s < 4; ++s) bv[s] = *(const f32x4*)(bp + s * 16 + g * 4);

        f32x4 acc[4] = {};
        #pragma unroll
        for (int s = 0; s < 4; ++s) {
            bf16x8 a0 = *(const bf16x8*)&Kl[cur][(s * 16 + ql) * LDE + g * 8];
            acc[s] = __builtin_amdgcn_mfma_f32_16x16x32_bf16(a0, qfrag0, acc[s], 0, 0, 0);
            bf16x8 a1 = *(const bf16x8*)&Kl[cur][(s * 16 + ql) * LDE + 32 + g * 8];
            acc[s] = __builtin_amdgcn_mfma_f32_16x16x32_bf16(a1, qfrag1, acc[s], 0, 0, 0);
        }
        #pragma unroll
        for (int s = 0; s < 4; ++s) {
            f32x4 x = acc[s] * SCALE + bv[s];
            lacc[0] += __expf(x[0]);
            lacc[1] += __expf(x[1]);
            lacc[2] += __expf(x[2]);
            lacc[3] += __expf(x[3]);
        }
        if (more)  // write-late: latency hidden under this iter's compute
            *(bf16x8*)&Kl[cur ^ 1][srow * LDE + sch * 8] = kreg;
        SOFT_BARRIER();
    }
    float l_run = lacc[0] + lacc[1] + lacc[2] + lacc[3];
    l_run += __shfl_xor(l_run, 16);
    l_run += __shfl_xor(l_run, 32);
    const float inv_l = 1.0f / l_run;

    // ================= phase 2: recompute, write W, accumulate PV ========
    *(bf16x8*)&Kl[0][srow * LDE + sch * 8] =
        *(const bf16x8*)(Kbh + (size_t)srow * DKK + sch * 8);
    *(bf16x8*)&Vl[0][srow * LDE + sch * 8] =
        *(const bf16x8*)(Vbh + (size_t)srow * TT + sch * 8);
    __syncthreads();

    f32x4 oacc[4] = {};            // O^T[d = m*16+4g+r][q_local]
    for (int kt = 0; kt < NKT; ++kt) {
        const int cur = kt & 1;
        const bool more = (kt + 1 < NKT);
        bf16x8 kreg, vreg;
        if (more) {
            kreg = *(const bf16x8*)(Kbh + ((size_t)(kt + 1) * KBLK + srow) * DKK + sch * 8);
            vreg = *(const bf16x8*)(Vbh + (size_t)srow * TT + (kt + 1) * KBLK + sch * 8);
        }
        const float* bp = biasRow + kt * KBLK;
        f32x4 bv[4];
        #pragma unroll
        for (int s = 0; s < 4; ++s) bv[s] = *(const f32x4*)(bp + s * 16 + g * 4);

        f32x4 acc[4] = {};
        #pragma unroll
        for (int s = 0; s < 4; ++s) {
            bf16x8 a0 = *(const bf16x8*)&Kl[cur][(s * 16 + ql) * LDE + g * 8];
            acc[s] = __builtin_amdgcn_mfma_f32_16x16x32_bf16(a0, qfrag0, acc[s], 0, 0, 0);
            bf16x8 a1 = *(const bf16x8*)&Kl[cur][(s * 16 + ql) * LDE + 32 + g * 8];
            acc[s] = __builtin_amdgcn_mfma_f32_16x16x32_bf16(a1, qfrag1, acc[s], 0, 0, 0);
        }
        // P = softmax weights (bf16), wave-private tile: row ql, cols s*16+4g+r
        #pragma unroll
        for (int s = 0; s < 4; ++s) {
            f32x4 x = acc[s] * SCALE + bv[s];
            bf16x4 pb = {(__bf16)(__expf(x[0]) * inv_l), (__bf16)(__expf(x[1]) * inv_l),
                         (__bf16)(__expf(x[2]) * inv_l), (__bf16)(__expf(x[3]) * inv_l)};
            *(bf16x4*)&Pl[w][ql * LDE + s * 16 + g * 4] = pb;
        }
        // PV: read own wave's P fragments (same-wave DS RAW is in-order)
        const bf16x8 bp0 = *(const bf16x8*)&Pl[w][ql * LDE + g * 8];
        const bf16x8 bp1 = *(const bf16x8*)&Pl[w][ql * LDE + 32 + g * 8];
        #pragma unroll
        for (int m = 0; m < 4; ++m) {
            bf16x8 av0 = *(const bf16x8*)&Vl[cur][(m * 16 + ql) * LDE + g * 8];
            oacc[m] = __builtin_amdgcn_mfma_f32_16x16x32_bf16(av0, bp0, oacc[m], 0, 0, 0);
            bf16x8 av1 = *(const bf16x8*)&Vl[cur][(m * 16 + ql) * LDE + 32 + g * 8];
            oacc[m] = __builtin_amdgcn_mfma_f32_16x16x32_bf16(av1, bp1, oacc[m], 0, 0, 0);
        }
        // per-wave cooperative W store: instr s2 covers 4 rows x 256B contiguous
        // NONTEMPORAL: keep the 512MB dead write stream out of L2/L3 so the
        // bias (re-read 4x) and K/V ws stay cache-resident.
        #pragma unroll
        for (int s2 = 0; s2 < 4; ++s2) {
            const int wr = s2 * 4 + g;                 // row 0..15 within wave
            bf16x4 pw = *(const bf16x4*)&Pl[w][wr * LDE + ql * 4];
            f32x4 ow = {(float)pw[0], (float)pw[1], (float)pw[2], (float)pw[3]};
            __builtin_nontemporal_store(ow,
                (f32x4*)(Wp + ((size_t)bh * TT + qt * QB + w * 16 + wr) * TT
                             + kt * KBLK + ql * 4));
        }
        if (more) {  // write-late staging, then the soft barrier
            *(bf16x8*)&Kl[cur ^ 1][srow * LDE + sch * 8] = kreg;
            *(bf16x8*)&Vl[cur ^ 1][srow * LDE + sch * 8] = vreg;
        }
        SOFT_BARRIER();
    }

    // ---- store O (nontemporal; write-once) ----
    float* Orow = Op + ((size_t)bh * TT + q_glob) * DKK;
    #pragma unroll
    for (int m = 0; m < 4; ++m)
        __builtin_nontemporal_store(oacc[m], (f32x4*)(Orow + m * 16 + g * 4));
}

extern "C" void kernel_launch(void* const* d_in, const int* in_sizes, int n_in,
                              void* d_out, int out_size, void* d_ws, size_t ws_size,
                              hipStream_t stream) {
    const float* Q  = (const float*)d_in[0];
    const float* K  = (const float*)d_in[1];
    const float* V  = (const float*)d_in[2];
    const float* Bs = (const float*)d_in[3];
    float* Out = (float*)d_out;
    float* W   = Out + (size_t)NBB * NHH * TT * DKK;

    const size_t nElem = (size_t)NBB * NHH * TT * DKK;
    __bf16* Kb = (__bf16*)d_ws;
    __bf16* Vt = Kb + nElem;

    cast_k_kernel<<<dim3(nElem / 8 / 256), dim3(256), 0, stream>>>(K, Kb);
    vt_kernel<<<dim3(TT / 64, NBB * NHH), dim3(256), 0, stream>>>(V, Vt);
    sdpa_main<<<dim3((TT / QB) * NBB * NHH), dim3(512), 0, stream>>>(Q, Bs, Kb, Vt, Out, W);
}